// Round 1
// baseline (644.742 us; speedup 1.0000x reference)
//
#include <hip/hip_runtime.h>

#define EPS 1e-6f
#define V_LO 0.95f
#define V_HI 1.05f

// ---------------------------------------------------------------------------
// Kernel 1: per-edge flows, scatter-add into p_flow/q_flow via fp32 atomics.
// node_features table is 1.6 MB -> L2-resident, gathers are cheap.
// ---------------------------------------------------------------------------
__global__ void pf_edge_kernel(const float* __restrict__ nf,
                               const int* __restrict__ ei,     // (2, E) row-major: [0..E)=src, [E..2E)=dst
                               const float* __restrict__ probs,
                               const float* __restrict__ params, // (E,2)
                               float* __restrict__ p_flow,
                               float* __restrict__ q_flow,
                               int n_edges) {
    int e = blockIdx.x * blockDim.x + threadIdx.x;
    int stride = gridDim.x * blockDim.x;
    for (; e < n_edges; e += stride) {
        int src = ei[e];
        int dst = ei[n_edges + e];
        float2 v   = *reinterpret_cast<const float2*>(&nf[(size_t)src * 4]);
        float2 pr  = *reinterpret_cast<const float2*>(&params[(size_t)e * 2]);
        float prob = probs[e];
        float v2 = v.x * v.x + v.y * v.y;
        float pe = v2 / (pr.x + EPS) * prob;
        float qe = v2 / (pr.y + EPS) * prob;
        atomicAdd(&p_flow[src], pe);
        atomicAdd(&q_flow[src], qe);
        if (src != dst) {
            atomicAdd(&p_flow[dst], pe);
            atomicAdd(&q_flow[dst], qe);
        }
    }
}

// ---------------------------------------------------------------------------
// Kernel 2: per-node loss terms, block reduction, one atomic per block.
// ---------------------------------------------------------------------------
__global__ void pf_node_kernel(const float* __restrict__ nf,
                               const float* __restrict__ p_flow,
                               const float* __restrict__ q_flow,
                               float* __restrict__ acc,
                               int n_nodes) {
    int i = blockIdx.x * blockDim.x + threadIdx.x;
    float c = 0.0f;
    if (i < n_nodes) {
        float4 f = *reinterpret_cast<const float4*>(&nf[(size_t)i * 4]);
        float pb = f.z + p_flow[i];
        float qb = f.w + q_flow[i];
        float vmag = sqrtf(f.x * f.x + f.y * f.y);
        float lv = fmaxf(V_LO - vmag, 0.0f);
        float uv = fmaxf(vmag - V_HI, 0.0f);
        c = pb * pb + qb * qb + lv * lv + uv * uv;
    }
    // wave-64 shuffle reduction
    #pragma unroll
    for (int off = 32; off > 0; off >>= 1)
        c += __shfl_down(c, off);
    __shared__ float wsum[4];
    int lane = threadIdx.x & 63;
    int wid  = threadIdx.x >> 6;
    if (lane == 0) wsum[wid] = c;
    __syncthreads();
    if (threadIdx.x == 0) {
        float s = 0.0f;
        int nw = blockDim.x >> 6;
        for (int w = 0; w < nw; ++w) s += wsum[w];
        atomicAdd(acc, s);
    }
}

__global__ void pf_finalize_kernel(const float* __restrict__ acc,
                                   float* __restrict__ out,
                                   float inv_n) {
    out[0] = acc[0] * inv_n;
}

extern "C" void kernel_launch(void* const* d_in, const int* in_sizes, int n_in,
                              void* d_out, int out_size, void* d_ws, size_t ws_size,
                              hipStream_t stream) {
    const float* nf     = (const float*)d_in[0];   // (N,4) f32
    const int*   ei     = (const int*)d_in[1];     // (2,E) int
    const float* probs  = (const float*)d_in[2];   // (E,) f32
    const float* params = (const float*)d_in[3];   // (E,2) f32

    int n_nodes = in_sizes[0] / 4;
    int n_edges = in_sizes[2];

    float* p_flow = (float*)d_ws;
    float* q_flow = p_flow + n_nodes;
    float* acc    = q_flow + n_nodes;

    // zero flows + accumulator every call (graph replay does not re-poison)
    hipMemsetAsync(d_ws, 0, (size_t)(2 * n_nodes + 1) * sizeof(float), stream);

    pf_edge_kernel<<<2048, 256, 0, stream>>>(nf, ei, probs, params,
                                             p_flow, q_flow, n_edges);

    int nblocks = (n_nodes + 255) / 256;
    pf_node_kernel<<<nblocks, 256, 0, stream>>>(nf, p_flow, q_flow, acc, n_nodes);

    pf_finalize_kernel<<<1, 1, 0, stream>>>(acc, (float*)d_out,
                                            1.0f / (float)n_nodes);
}

// Round 2
// 640.137 us; speedup vs baseline: 1.0072x; 1.0072x over previous
//
#include <hip/hip_runtime.h>

#define EPS 1e-6f
#define V_LO 0.95f
#define V_HI 1.05f
#define NXCD 8

// Physical XCD id of the CU this wave runs on (verified on gfx950, learn_hip m09).
__device__ __forceinline__ int xcc_id() {
    int x;
    asm volatile("s_getreg_b32 %0, hwreg(HW_REG_XCC_ID)" : "=s"(x));
    return x & (NXCD - 1);
}

// ---------------------------------------------------------------------------
// Kernel 1: per-edge flows. PRIV=true: scatter-add into the per-XCD private
// copy with WORKGROUP-scope atomics -> executes in the local XCD's L2 (all
// writers of copy k are physically on XCD k). PRIV=false: single copy,
// agent-scope atomics (slow but always correct fallback).
// flow layout: copies of n_nodes float2 (p,q interleaved).
// ---------------------------------------------------------------------------
template <bool PRIV>
__global__ void pf_edge_kernel(const float* __restrict__ nf,
                               const int* __restrict__ ei,       // (2,E): [0..E)=src, [E..2E)=dst
                               const float* __restrict__ probs,
                               const float2* __restrict__ params, // (E,2) as float2
                               float2* __restrict__ flow,
                               int n_edges, int n_nodes) {
    float2* myflow = flow;
    if (PRIV) myflow += (size_t)xcc_id() * n_nodes;

    int e = blockIdx.x * blockDim.x + threadIdx.x;
    int stride = gridDim.x * blockDim.x;
    for (; e < n_edges; e += stride) {
        int src = ei[e];
        int dst = ei[n_edges + e];
        float2 v   = *reinterpret_cast<const float2*>(&nf[(size_t)src * 4]);
        float2 pr  = params[e];
        float prob = probs[e];
        float v2 = v.x * v.x + v.y * v.y;
        float pe = v2 / (pr.x + EPS) * prob;
        float qe = v2 / (pr.y + EPS) * prob;
        if (PRIV) {
            __hip_atomic_fetch_add(&myflow[src].x, pe, __ATOMIC_RELAXED, __HIP_MEMORY_SCOPE_WORKGROUP);
            __hip_atomic_fetch_add(&myflow[src].y, qe, __ATOMIC_RELAXED, __HIP_MEMORY_SCOPE_WORKGROUP);
            if (src != dst) {
                __hip_atomic_fetch_add(&myflow[dst].x, pe, __ATOMIC_RELAXED, __HIP_MEMORY_SCOPE_WORKGROUP);
                __hip_atomic_fetch_add(&myflow[dst].y, qe, __ATOMIC_RELAXED, __HIP_MEMORY_SCOPE_WORKGROUP);
            }
        } else {
            atomicAdd(&myflow[src].x, pe);
            atomicAdd(&myflow[src].y, qe);
            if (src != dst) {
                atomicAdd(&myflow[dst].x, pe);
                atomicAdd(&myflow[dst].y, qe);
            }
        }
    }
}

// ---------------------------------------------------------------------------
// Kernel 2: per-node loss terms; sums the NC flow copies, block-reduces,
// one atomic per block.
// ---------------------------------------------------------------------------
__global__ void pf_node_kernel(const float* __restrict__ nf,
                               const float2* __restrict__ flow,
                               float* __restrict__ acc,
                               int n_nodes, int ncopies) {
    int i = blockIdx.x * blockDim.x + threadIdx.x;
    float c = 0.0f;
    if (i < n_nodes) {
        float4 f = *reinterpret_cast<const float4*>(&nf[(size_t)i * 4]);
        float p = f.z, q = f.w;
        for (int k = 0; k < ncopies; ++k) {
            float2 fl = flow[(size_t)k * n_nodes + i];
            p += fl.x;
            q += fl.y;
        }
        float vmag = sqrtf(f.x * f.x + f.y * f.y);
        float lv = fmaxf(V_LO - vmag, 0.0f);
        float uv = fmaxf(vmag - V_HI, 0.0f);
        c = p * p + q * q + lv * lv + uv * uv;
    }
    #pragma unroll
    for (int off = 32; off > 0; off >>= 1)
        c += __shfl_down(c, off);
    __shared__ float wsum[4];
    int lane = threadIdx.x & 63;
    int wid  = threadIdx.x >> 6;
    if (lane == 0) wsum[wid] = c;
    __syncthreads();
    if (threadIdx.x == 0) {
        float s = 0.0f;
        int nw = blockDim.x >> 6;
        for (int w = 0; w < nw; ++w) s += wsum[w];
        atomicAdd(acc, s);
    }
}

__global__ void pf_finalize_kernel(const float* __restrict__ acc,
                                   float* __restrict__ out,
                                   float inv_n) {
    out[0] = acc[0] * inv_n;
}

extern "C" void kernel_launch(void* const* d_in, const int* in_sizes, int n_in,
                              void* d_out, int out_size, void* d_ws, size_t ws_size,
                              hipStream_t stream) {
    const float*  nf     = (const float*)d_in[0];    // (N,4) f32
    const int*    ei     = (const int*)d_in[1];      // (2,E) int
    const float*  probs  = (const float*)d_in[2];    // (E,) f32
    const float2* params = (const float2*)d_in[3];   // (E,2) f32

    int n_nodes = in_sizes[0] / 4;
    int n_edges = in_sizes[2];

    size_t per_copy_bytes = (size_t)n_nodes * sizeof(float2);
    bool priv = ws_size >= NXCD * per_copy_bytes + sizeof(float);
    int ncopies = priv ? NXCD : 1;

    float2* flow = (float2*)d_ws;
    float*  acc  = (float*)((char*)d_ws + (size_t)ncopies * per_copy_bytes);

    // zero flow copies + accumulator every call (graph replay does not re-poison)
    hipMemsetAsync(d_ws, 0, (size_t)ncopies * per_copy_bytes + sizeof(float), stream);

    if (priv) {
        pf_edge_kernel<true><<<2048, 256, 0, stream>>>(nf, ei, probs, params,
                                                       flow, n_edges, n_nodes);
    } else {
        pf_edge_kernel<false><<<2048, 256, 0, stream>>>(nf, ei, probs, params,
                                                        flow, n_edges, n_nodes);
    }

    int nblocks = (n_nodes + 255) / 256;
    pf_node_kernel<<<nblocks, 256, 0, stream>>>(nf, flow, acc, n_nodes, ncopies);

    pf_finalize_kernel<<<1, 1, 0, stream>>>(acc, (float*)d_out,
                                            1.0f / (float)n_nodes);
}